// Round 29
// baseline (923.493 us; speedup 1.0000x reference)
//
#include <hip/hip_runtime.h>
#include <hip/hip_bf16.h>

// Model dims (fixed)
#define DIMM 128
#define TT   40
#define BB   4096
#define NTOK (BB*TT)           // 163840
#define NLAY 3

typedef float f4 __attribute__((ext_vector_type(4)));
typedef float f32x4 __attribute__((ext_vector_type(4)));
typedef short bf16x8 __attribute__((ext_vector_type(8)));

__device__ __forceinline__ float bf2f(unsigned short u) {
    union { unsigned int i; float f; } v; v.i = ((unsigned int)u) << 16; return v.f;
}
__device__ __forceinline__ unsigned short f2bu(float f) {
    __hip_bfloat16 h = __float2bfloat16(f);
    return *reinterpret_cast<unsigned short*>(&h);
}
// tanh-form gelu via sigmoid
__device__ __forceinline__ float gelu_f(float v) {
    float z = 1.5957691216057308f * fmaf(0.044715f * v * v, v, v);
    return v / (1.f + __expf(-z));
}

// per-row mln stats from registers (16 lanes hold full row)
__device__ __forceinline__ void mln_rowstat(
    const float* v, const float* pgv, const float* pbv,
    float& m, float& rstd, float& mq)
{
    float s1 = 0.f, s2 = 0.f;
    #pragma unroll
    for (int nf = 0; nf < 8; ++nf) { s1 += v[nf]; s2 += v[nf]*v[nf]; }
    #pragma unroll
    for (int o = 1; o < 16; o <<= 1) { s1 += __shfl_xor(s1, o); s2 += __shfl_xor(s2, o); }
    m = s1 * (1.f/128.f);
    float var = s2 * (1.f/128.f) - m*m;
    rstd = rsqrtf(fmaxf(var, 0.f) + 1e-5f);
    float q = 0.f;
    #pragma unroll
    for (int nf = 0; nf < 8; ++nf) {
        float yv = (v[nf] - m) * rstd * pgv[nf] + pbv[nf];
        q += (nf < 2 ? -(yv*yv) : (yv*yv));
    }
    #pragma unroll
    for (int o = 1; o < 16; o <<= 1) q += __shfl_xor(q, o);
    mq = q;
}

// single-row mln A-fragments (16-row tile)
__device__ __forceinline__ void build_mln_frags1(
    bf16x8 a[4], const float* __restrict__ h, int row,
    const float* __restrict__ stats, float eps,
    const float* __restrict__ pg, const float* __restrict__ pb,
    const float* __restrict__ gg, const float* __restrict__ gb, int q)
{
    float m  = stats[(size_t)row*4 + 0];
    float rs = stats[(size_t)row*4 + 1];
    float mq = stats[(size_t)row*4 + 2];
    float s3 = 1.f / (sqrtf(fabsf(mq) + eps) + eps);
    float rss3 = rs * s3, mm = -m * rss3;
    #pragma unroll
    for (int ks = 0; ks < 4; ++ks) {
        int c0 = ks*32 + q*8;
        f4 x0 = *(const f4*)(h + (size_t)row*128 + c0);
        f4 x1 = *(const f4*)(h + (size_t)row*128 + c0 + 4);
        union { unsigned short u[8]; bf16x8 v; } o;
        #pragma unroll
        for (int j = 0; j < 4; ++j) {
            float g0 = gg[c0+j], g1 = gg[c0+j+4];
            float t0 = fmaf(x0[j], rss3, mm);
            float t1 = fmaf(x1[j], rss3, mm);
            o.u[j]   = f2bu(fmaf(g0 * pg[c0+j],   t0, fmaf(g0 * pb[c0+j],   s3, gb[c0+j])));
            o.u[j+4] = f2bu(fmaf(g1 * pg[c0+j+4], t1, fmaf(g1 * pb[c0+j+4], s3, gb[c0+j+4])));
        }
        a[ks] = o.v;
    }
}

// ---------------- pack ALL weights to bf16, transposed W^T[n][k] ----------------
__global__ __launch_bounds__(256) void pack_w_k(
    const float* __restrict__ qt, const float* __restrict__ kt,
    const float* __restrict__ qs, const float* __restrict__ ks,
    const float* __restrict__ vw, const float* __restrict__ ow,
    const float* __restrict__ w1, const float* __restrict__ w2,
    unsigned short* __restrict__ wqT, unsigned short* __restrict__ outT,
    unsigned short* __restrict__ ff1T, unsigned short* __restrict__ ff2T)
{
    int idx = blockIdx.x * 256 + threadIdx.x;          // 589824 total
    if (idx < 147456) {
        int i = idx / 49152, r = idx % 49152;
        int n = r / 128, k = r % 128;
        float v;
        if (n < 32)        v = qt[i*4096  + k*32  + n];
        else if (n < 64)   v = kt[i*4096  + k*32  + (n-32)];
        else if (n < 160)  v = qs[i*12288 + k*96  + (n-64)];
        else if (n < 256)  v = ks[i*12288 + k*96  + (n-160)];
        else               v = vw[i*16384 + k*128 + (n-256)];
        wqT[idx] = f2bu(v);
    } else if (idx < 196608) {
        int j = idx - 147456;
        int i = j / 16384, r = j % 16384;
        int n = r / 128, k = r % 128;
        outT[j] = f2bu(ow[i*16384 + k*128 + n]);
    } else if (idx < 393216) {
        int j = idx - 196608;
        int i = j / 65536, r = j % 65536;
        int n = r / 128, k = r % 128;
        ff1T[j] = f2bu(w1[i*65536 + k*512 + n]);
    } else {
        int j = idx - 393216;
        int i = j / 65536, r = j % 65536;
        int n = r / 512, k = r % 512;
        ff2T[j] = f2bu(w2[i*65536 + k*128 + n]);
    }
}

// ---------------- fused embedding + mln1 stats (layer 0) ----------------
__global__ __launch_bounds__(256) void embed_stats_k(
    const float* __restrict__ x, const float* __restrict__ ew,
    const float* __restrict__ eb, const float* __restrict__ pos,
    const float* __restrict__ pg, const float* __restrict__ pb,
    float* __restrict__ h, float* __restrict__ stats, float* __restrict__ partials)
{
    int wid = threadIdx.x >> 6, lane = threadIdx.x & 63;
    int tok = blockIdx.x * 4 + wid;
    int t = tok % TT;
    const float* xr = x + (size_t)tok * 6;
    float xv[6];
    #pragma unroll
    for (int k = 0; k < 6; ++k) xv[k] = xr[k];
    int d0 = lane, d1 = lane + 64;
    float x0 = eb[d0] + pos[t*128 + d0];
    float x1 = eb[d1] + pos[t*128 + d1];
    #pragma unroll
    for (int k = 0; k < 6; ++k) {
        x0 += xv[k] * ew[k*128 + d0];
        x1 += xv[k] * ew[k*128 + d1];
    }
    h[(size_t)tok*128 + d0] = x0;
    h[(size_t)tok*128 + d1] = x1;

    float s = x0 + x1;
    #pragma unroll
    for (int o = 32; o > 0; o >>= 1) s += __shfl_xor(s, o);
    float m = s * (1.f / 128.f);
    float e0 = x0 - m, e1 = x1 - m;
    float v = e0*e0 + e1*e1;
    #pragma unroll
    for (int o = 32; o > 0; o >>= 1) v += __shfl_xor(v, o);
    float rstd = rsqrtf(v * (1.f / 128.f) + 1e-5f);
    float y0 = e0 * rstd * pg[lane]      + pb[lane];
    float y1 = e1 * rstd * pg[lane + 64] + pb[lane + 64];
    float q = (lane < 32 ? -(y0*y0) : (y0*y0)) + y1*y1;
    #pragma unroll
    for (int o = 32; o > 0; o >>= 1) q += __shfl_xor(q, o);
    if (lane == 0) {
        stats[(size_t)tok*4 + 0] = m;
        stats[(size_t)tok*4 + 1] = rstd;
        stats[(size_t)tok*4 + 2] = q;
    }
    __shared__ float pm[4];
    if (lane == 0) pm[wid] = fabsf(q);
    __syncthreads();
    if (threadIdx.x == 0) partials[blockIdx.x] = (pm[0] + pm[1]) + (pm[2] + pm[3]);
}

// ---------------- reduce partials -> eps scalar ----------------
__global__ __launch_bounds__(1024) void reduce_eps_k(
    const float* __restrict__ partials, int n, float* __restrict__ scal)
{
    float s = 0.f;
    for (int i = threadIdx.x; i < n; i += 1024) s += partials[i];
    __shared__ float sm[1024];
    sm[threadIdx.x] = s;
    __syncthreads();
    for (int o = 512; o > 0; o >>= 1) {
        if (threadIdx.x < o) sm[threadIdx.x] += sm[threadIdx.x + o];
        __syncthreads();
    }
    if (threadIdx.x == 0) {
        float mean = sm[0] / (float)NTOK;
        scal[0] = fmaxf(0.01f * mean, 1e-5f);
    }
}

// ---------------- FUSED qkv GEMM + attention + out-proj + mln2 stats ----------------
// One block per batch element. qkv output lives only in LDS (no scratch round-trip).
__global__ __launch_bounds__(256) void qkvattn_k(
    const float* __restrict__ hsrc,
    const float* __restrict__ stats_in, const float* __restrict__ scal,
    const float* __restrict__ pg, const float* __restrict__ pb,
    const float* __restrict__ gg, const float* __restrict__ gb,
    const unsigned short* __restrict__ BT,    // Wq [384 n][128 k] bf16
    const float* __restrict__ wsp,
    const unsigned short* __restrict__ outT,  // [128 n][128 k] bf16
    const float* __restrict__ bias,
    float* __restrict__ hres,
    const float* __restrict__ pre_g, const float* __restrict__ pre_b,
    float* __restrict__ stats, float* __restrict__ partials)
{
    // layout: [0,16384) VtL | [16384,40960) PlL | [40960,78592) qkvL [48][392] bf16
    // WqC overlays [0,32768) during qkv phase; phase2 Ol/Wl overlay [0,45056).
    __shared__ unsigned char lds[78592];
    __shared__ float sm[16];
    const int b = blockIdx.x, tid = threadIdx.x;
    const int wid = tid >> 6, lane = tid & 63;
    const int q4 = lane >> 4, l15 = lane & 15;

    unsigned char* VtL = lds;
    unsigned char* PlL = lds + 16384;
    unsigned short* qkvL = (unsigned short*)(lds + 40960);   // [48][392]
    unsigned char* WqC = lds;

    // ---- qkv phase: qkvL[t][0..383] = mln1(h[b,t]) @ Wq ----
    bf16x8 a[3][4];
    #pragma unroll
    for (int mt = 0; mt < 3; ++mt) {
        int t0 = 16*mt + l15; if (t0 > 39) t0 = 39;
        build_mln_frags1(a[mt], hsrc, b*TT + t0, stats_in, scal[0], pg, pb, gg, gb, q4);
    }
    const unsigned char* BTb = (const unsigned char*)BT;
    for (int nc = 0; nc < 3; ++nc) {
        __syncthreads();
        {   // stage Wq chunk nc: 128 n-rows x 256 B, swz (row&7)<<4
            int row = tid >> 1, half = tid & 1;
            #pragma unroll
            for (int jj = 0; jj < 8; ++jj) {
                int colb = half*128 + jj*16;
                uint4 v = *(const uint4*)(BTb + (size_t)(nc*128 + row)*256 + colb);
                *(uint4*)(WqC + row*256 + (colb ^ ((row & 7) << 4))) = v;
            }
        }
        __syncthreads();
        f32x4 acc[3][2] = {};
        #pragma unroll
        for (int ks = 0; ks < 4; ++ks)
            #pragma unroll
            for (int nf2 = 0; nf2 < 2; ++nf2) {
                int row = (wid*2 + nf2)*16 + l15;
                bf16x8 bfr = *(const bf16x8*)(WqC + row*256 + ((ks*64 + q4*16) ^ ((row & 7) << 4)));
                #pragma unroll
                for (int mt = 0; mt < 3; ++mt)
                    acc[mt][nf2] = __builtin_amdgcn_mfma_f32_16x16x32_bf16(a[mt][ks], bfr, acc[mt][nf2], 0, 0, 0);
            }
        #pragma unroll
        for (int mt = 0; mt < 3; ++mt)
            #pragma unroll
            for (int nf2 = 0; nf2 < 2; ++nf2)
                #pragma unroll
                for (int r = 0; r < 4; ++r) {
                    int row = 16*mt + 4*q4 + r;                       // 0..47 (pad rows >39 never read)
                    int col = nc*128 + (wid*2 + nf2)*16 + l15;
                    qkvL[(size_t)row*392 + col] = f2bu(acc[mt][nf2][r]);
                }
    }
    __syncthreads();   // qkvL complete; WqC readers done -> region reusable

    // ---- attention phase (reads qkvL, stride 392 shorts) ----
    // zero P pad cols 48..63
    for (int e = tid; e < 1536; e += 256) {
        int hh = e / 384, rem = e - hh*384;
        int row = rem >> 3, c = rem & 7;
        int byte = hh*6144 + ((row*128 + 96 + 4*c) ^ ((row & 7) << 4));
        *(unsigned int*)(PlL + byte) = 0u;
    }
    // zero V pad s 40..63
    for (int e = tid; e < 1536; e += 256) {
        int hh = e / 384, rem = e - hh*384;
        int d = rem / 12, sc2 = rem - d*12;
        int s = 40 + 2*sc2;
        int byte = hh*4096 + ((d*128 + s*2) ^ (((d >> 3) & 7) << 4));
        *(unsigned int*)(VtL + byte) = 0u;
    }
    // stage V transposed from qkvL
    for (int e = tid; e < 640; e += 256) {
        int s = e >> 4, ck = e & 15;
        union { bf16x8 v; unsigned short u[8]; } g;
        g.v = *(const bf16x8*)(qkvL + (size_t)s*392 + 256 + ck*8);
        int hh = ck >> 2, d0 = (ck & 3) * 8;
        #pragma unroll
        for (int j = 0; j < 8; ++j) {
            int d = d0 + j;
            int byte = hh*4096 + ((d*128 + s*2) ^ (((d >> 3) & 7) << 4));
            *(unsigned short*)(VtL + byte) = g.u[j];
        }
    }
    __syncthreads();

    const int h = tid >> 6;
    const unsigned char* Vt = VtL + h*4096;
    unsigned char* Pl = PlL + h*6144;

    const int qcol = (h == 0) ? 0  : 32  + h*32;
    const int kcol = (h == 0) ? 32 : 128 + h*32;
    const float scale = 0.17677669529663687f;   // 32^-0.5
    const float wmul = (h == 0) ? (-scale / (1.f + __expf(-wsp[0]))) : scale;

    bf16x8 aq[3], bk[3];
    #pragma unroll
    for (int mt = 0; mt < 3; ++mt) {
        int t = l15 + 16*mt; if (t > 39) t = 39;
        aq[mt] = *(const bf16x8*)(qkvL + (size_t)t*392 + qcol + q4*8);
    }
    #pragma unroll
    for (int jt = 0; jt < 3; ++jt) {
        int s = l15 + 16*jt; if (s > 39) s = 39;
        bk[jt] = *(const bf16x8*)(qkvL + (size_t)s*392 + kcol + q4*8);
    }
    f32x4 sc[3][3] = {};
    #pragma unroll
    for (int mt = 0; mt < 3; ++mt)
        #pragma unroll
        for (int jt = 0; jt < 3; ++jt)
            sc[mt][jt] = __builtin_amdgcn_mfma_f32_16x16x32_bf16(aq[mt], bk[jt], sc[mt][jt], 0, 0, 0);

    const bool mask2 = (l15 >= 8);
    float inv[3][4];
    #pragma unroll
    for (int mt = 0; mt < 3; ++mt) {
        #pragma unroll
        for (int r = 0; r < 4; ++r) {
            float s0 = wmul * sc[mt][0][r];
            float s1 = wmul * sc[mt][1][r];
            float s2 = mask2 ? -1e30f : wmul * sc[mt][2][r];
            float mx = fmaxf(fmaxf(s0, s1), s2);
            #pragma unroll
            for (int o = 1; o < 16; o <<= 1) mx = fmaxf(mx, __shfl_xor(mx, o));
            float e0 = __expf(s0 - mx), e1 = __expf(s1 - mx), e2 = __expf(s2 - mx);
            float sum = e0 + e1 + e2;
            #pragma unroll
            for (int o = 1; o < 16; o <<= 1) sum += __shfl_xor(sum, o);
            inv[mt][r] = 1.f / sum;
            int row = 16*mt + 4*q4 + r;
            int rsw = (row & 7) << 4;
            *(unsigned short*)(Pl + ((row*128 + l15*2       ) ^ rsw)) = f2bu(e0);
            *(unsigned short*)(Pl + ((row*128 + 32 + l15*2  ) ^ rsw)) = f2bu(e1);
            *(unsigned short*)(Pl + ((row*128 + 64 + l15*2  ) ^ rsw)) = f2bu(e2);
        }
    }

    f32x4 oacc[3][2] = {};
    #pragma unroll
    for (int ks2 = 0; ks2 < 2; ++ks2) {
        bf16x8 bv[2];
        #pragma unroll
        for (int nt = 0; nt < 2; ++nt) {
            int d = l15 + 16*nt;
            bv[nt] = *(const bf16x8*)(Vt + ((d*128 + 64*ks2 + 16*q4) ^ (((d >> 3) & 7) << 4)));
        }
        #pragma unroll
        for (int mt = 0; mt < 3; ++mt) {
            int row = l15 + 16*mt;
            bf16x8 pa = *(const bf16x8*)(Pl + ((row*128 + 64*ks2 + 16*q4) ^ ((row & 7) << 4)));
            #pragma unroll
            for (int nt = 0; nt < 2; ++nt)
                oacc[mt][nt] = __builtin_amdgcn_mfma_f32_16x16x32_bf16(pa, bv[nt], oacc[mt][nt], 0, 0, 0);
        }
    }

    // -------- phase 2: out-proj fused --------
    __syncthreads();          // all V/P/qkvL reads done; lds reusable
    unsigned char* Ol = lds;              // [48 row][256 B], swz (row&7)<<4
    unsigned char* Wl = lds + 12288;      // [128 n][256 B],  swz (row&7)<<4

    #pragma unroll
    for (int mt = 0; mt < 3; ++mt) {
        #pragma unroll
        for (int r = 0; r < 4; ++r) {
            int row = 16*mt + 4*q4 + r;
            float iv = inv[mt][r];
            int rsw = (row & 7) << 4;
            #pragma unroll
            for (int nt = 0; nt < 2; ++nt) {
                int colb = (h*32 + nt*16 + l15) * 2;
                *(unsigned short*)(Ol + ((row*256 + colb) ^ rsw)) = f2bu(oacc[mt][nt][r] * iv);
            }
        }
    }
    // stage Wout
    {
        const unsigned char* BTo = (const unsigned char*)outT;
        int row = tid >> 1, half = tid & 1;
        #pragma unroll
        for (int jj = 0; jj < 8; ++jj) {
            int colb = half*128 + jj*16;
            uint4 v = *(const uint4*)(BTo + (size_t)row*256 + colb);
            *(uint4*)(Wl + row*256 + (colb ^ ((row & 7) << 4))) = v;
        }
    }
    if (h == 3 && l15 == 0) sm[12 + q4] = 0.f;
    __syncthreads();

    if (h < 3) {
        int arow = 16*h + l15;
        bf16x8 ao[4];
        #pragma unroll
        for (int ks = 0; ks < 4; ++ks)
            ao[ks] = *(const bf16x8*)(Ol + arow*256 + ((ks*64 + q4*16) ^ ((arow & 7) << 4)));
        f32x4 oc[8] = {};
        #pragma unroll
        for (int ks = 0; ks < 4; ++ks)
            #pragma unroll
            for (int nf = 0; nf < 8; ++nf) {
                int brow = nf*16 + l15;
                bf16x8 bo = *(const bf16x8*)(Wl + brow*256 + ((ks*64 + q4*16) ^ ((brow & 7) << 4)));
                oc[nf] = __builtin_amdgcn_mfma_f32_16x16x32_bf16(ao[ks], bo, oc[nf], 0, 0, 0);
            }

        float bv[8], pgv[8], pbv[8];
        #pragma unroll
        for (int nf = 0; nf < 8; ++nf) {
            int c = nf*16 + l15;
            bv[nf] = bias[c]; pgv[nf] = pre_g[c]; pbv[nf] = pre_b[c];
        }
        float amq = 0.f;
        #pragma unroll
        for (int r = 0; r < 4; ++r) {
            int t = 16*h + 4*q4 + r;
            if (t < 40) {
                int row = b*TT + t;
                float* hr = hres + (size_t)row*128;
                float v[8];
                #pragma unroll
                for (int nf = 0; nf < 8; ++nf) {
                    float hv = hr[nf*16 + l15] + oc[nf][r] + bv[nf];
                    hr[nf*16 + l15] = hv;
                    v[nf] = hv;
                }
                float m, rstd, mq;
                mln_rowstat(v, pgv, pbv, m, rstd, mq);
                if (l15 == 0) {
                    stats[(size_t)row*4 + 0] = m;
                    stats[(size_t)row*4 + 1] = rstd;
                    stats[(size_t)row*4 + 2] = mq;
                }
                amq += fabsf(mq);
            }
        }
        if (l15 == 0) sm[h*4 + q4] = amq;
    }
    __syncthreads();
    if (tid == 0) {
        float s = 0.f;
        #pragma unroll
        for (int j = 0; j < 16; ++j) s += sm[j];
        partials[b] = s;
    }
}

// ---------------- fused FFN: 8-wave/128-row block (16 rows/wave); W tiles in swizzled LDS ----------------
__global__ __launch_bounds__(512) void ffn_k(
    const float* __restrict__ hsrc,
    const float* __restrict__ stats_in, const float* __restrict__ scal,
    const float* __restrict__ m2_pre_g, const float* __restrict__ m2_pre_b,
    const float* __restrict__ m2_g, const float* __restrict__ m2_b,
    const unsigned short* __restrict__ W1T,   // [512][128] bf16
    const float* __restrict__ b1,
    const unsigned short* __restrict__ W2T,   // [128][512] bf16
    const float* __restrict__ b2,
    float* __restrict__ h,
    const float* __restrict__ pre_g, const float* __restrict__ pre_b,
    float* __restrict__ stats, float* __restrict__ partials)
{
    __shared__ unsigned char W1l[16384];      // [64 mid][256 B], swz (row&7)<<4
    __shared__ unsigned char W2l[16384];      // [128 n][128 B],  swz (row&7)<<4
    __shared__ unsigned char Ps[8][16*144];   // per-wave gelu mid (16 rows)
    __shared__ float sm[32];
    const int tid = threadIdx.x, wid = tid >> 6, lane = tid & 63;
    const int q = lane >> 4, l15 = lane & 15;
    const int row0 = blockIdx.x * 128;
    const int wrow = row0 + wid * 16;
    unsigned char* Pw = Ps[wid];

    bf16x8 a[4];
    build_mln_frags1(a, hsrc, wrow + l15,
                     stats_in, scal[0], m2_pre_g, m2_pre_b, m2_g, m2_b, q);

    float b2v[8];
    #pragma unroll
    for (int nf = 0; nf < 8; ++nf) b2v[nf] = b2[nf*16 + l15];

    f32x4 acc2[8] = {};
    const unsigned char* W1b = (const unsigned char*)W1T;
    const unsigned char* W2b = (const unsigned char*)W2T;

    for (int c = 0; c < 8; ++c) {
        __syncthreads();
        // stage W1 chunk: 64 mid-rows x 256 B (512 threads, 32B each)
        {
            int row = tid >> 3, seg = tid & 7;
            #pragma unroll
            for (int jj = 0; jj < 2; ++jj) {
                int colb = seg*32 + jj*16;
                uint4 v = *(const uint4*)(W1b + (size_t)(c*64 + row)*256 + colb);
                *(uint4*)(W1l + row*256 + (colb ^ ((row & 7) << 4))) = v;
            }
        }
        // stage W2 chunk: 128 n-rows x 128 B (512 threads, 32B each)
        {
            int row = tid >> 2, seg = tid & 3;
            #pragma unroll
            for (int jj = 0; jj < 2; ++jj) {
                int colb = seg*32 + jj*16;
                uint4 v = *(const uint4*)(W2b + (size_t)row*1024 + c*128 + colb);
                *(uint4*)(W2l + row*128 + (colb ^ ((row & 7) << 4))) = v;
            }
        }
        __syncthreads();
        // gemm1: P = A @ W1c  (bias folded into acc init)
        float bbv[4];
        #pragma unroll
        for (int nf = 0; nf < 4; ++nf) bbv[nf] = b1[c*64 + nf*16 + l15];
        f32x4 acc1[4];
        #pragma unroll
        for (int nf = 0; nf < 4; ++nf)
            acc1[nf] = f32x4{bbv[nf], bbv[nf], bbv[nf], bbv[nf]};
        #pragma unroll
        for (int ks = 0; ks < 4; ++ks)
            #pragma unroll
            for (int nf = 0; nf < 4; ++nf) {
                int row = nf*16 + l15;
                bf16x8 b = *(const bf16x8*)(W1l + row*256 + ((ks*64 + q*16) ^ ((row & 7) << 4)));
                acc1[nf] = __builtin_amdgcn_mfma_f32_16x16x32_bf16(a[ks], b, acc1[nf], 0, 0, 0);
            }
        #pragma unroll
        for (int nf = 0; nf < 4; ++nf) {
            #pragma unroll
            for (int r = 0; r < 4; ++r) {
                float v = gelu_f(acc1[nf][r]);
                *(unsigned short*)(Pw + (q*4 + r)*144 + (nf*16 + l15)*2) = f2bu(v);
            }
        }
        #pragma unroll
        for (int ks2 = 0; ks2 < 2; ++ks2) {
            bf16x8 a2 = *(const bf16x8*)(Pw + l15*144 + ks2*64 + q*16);
            #pragma unroll
            for (int nf = 0; nf < 8; ++nf) {
                int row = nf*16 + l15;
                bf16x8 b = *(const bf16x8*)(W2l + row*128 + ((ks2*64 + q*16) ^ ((row & 7) << 4)));
                acc2[nf] = __builtin_amdgcn_mfma_f32_16x16x32_bf16(a2, b, acc2[nf], 0, 0, 0);
            }
        }
    }

    float pgv[8], pbv[8];
    #pragma unroll
    for (int nf = 0; nf < 8; ++nf) { pgv[nf] = pre_g[nf*16 + l15]; pbv[nf] = pre_b[nf*16 + l15]; }
    float amq = 0.f;
    #pragma unroll
    for (int r = 0; r < 4; ++r) {
        int row = wrow + q*4 + r;
        float* hr = h + (size_t)row*128;
        float v[8];
        #pragma unroll
        for (int nf = 0; nf < 8; ++nf) {
            float hv = hr[nf*16 + l15] + acc2[nf][r] + b2v[nf];
            hr[nf*16 + l15] = hv;
            v[nf] = hv;
        }
        float m, rstd, mq;
        mln_rowstat(v, pgv, pbv, m, rstd, mq);
        if (l15 == 0) {
            stats[(size_t)row*4 + 0] = m;
            stats[(size_t)row*4 + 1] = rstd;
            stats[(size_t)row*4 + 2] = mq;
        }
        amq += fabsf(mq);
    }
    if (l15 == 0) sm[wid*4 + q] = amq;
    __syncthreads();
    if (tid == 0) {
        float s = 0.f;
        #pragma unroll
        for (int j = 0; j < 32; ++j) s += sm[j];
        partials[blockIdx.x] = s;
    }
}

// ---------------- head: final mln (last token only) + @traj_w + traj_b ----------------
__global__ __launch_bounds__(128) void head_k(
    const float* __restrict__ h, const float* __restrict__ stats, const float* __restrict__ scal,
    const float* __restrict__ pg, const float* __restrict__ pb,
    const float* __restrict__ gg, const float* __restrict__ gb,
    const float* __restrict__ tw, const float* __restrict__ tb,
    float* __restrict__ out)
{
    int b = blockIdx.x, tid = threadIdx.x;
    int tok = b*TT + (TT - 1);
    __shared__ float ys[128];
    float eps = scal[0];
    float m  = stats[(size_t)tok*4 + 0];
    float rs = stats[(size_t)tok*4 + 1];
    float mq = stats[(size_t)tok*4 + 2];
    float s3 = 1.f / (sqrtf(fabsf(mq) + eps) + eps);
    float x = h[(size_t)tok*128 + tid];
    ys[tid] = gg[tid] * (((x - m) * rs * pg[tid] + pb[tid]) * s3) + gb[tid];
    __syncthreads();
    if (tid < 120) {
        float acc = tb[tid];
        #pragma unroll 4
        for (int d = 0; d < 128; ++d) acc += ys[d] * tw[d*120 + tid];
        out[(size_t)b*120 + tid] = acc;
    }
}

extern "C" void kernel_launch(void* const* d_in, const int* in_sizes, int n_in,
                              void* d_out, int out_size, void* d_ws, size_t ws_size,
                              hipStream_t stream) {
    const float* x        = (const float*)d_in[0];
    const float* embed_w  = (const float*)d_in[1];
    const float* embed_b  = (const float*)d_in[2];
    const float* pos      = (const float*)d_in[3];
    const float* qt_w     = (const float*)d_in[4];
    const float* kt_w     = (const float*)d_in[5];
    const float* qs_w     = (const float*)d_in[6];
    const float* ks_w     = (const float*)d_in[7];
    const float* v_w      = (const float*)d_in[8];
    const float* out_w    = (const float*)d_in[9];
    const float* out_b    = (const float*)d_in[10];
    const float* w_sigma  = (const float*)d_in[11];
    const float* n1_pre_g = (const float*)d_in[12];
    const float* n1_pre_b = (const float*)d_in[13];
    const float* n1_g     = (const float*)d_in[14];
    const float* n1_b     = (const float*)d_in[15];
    const float* n2_pre_g = (const float*)d_in[16];
    const float* n2_pre_b = (const float*)d_in[17];
    const float* n2_g     = (const float*)d_in[18];
    const float* n2_b     = (const float*)d_in[19];
    const float* ff_w1    = (const float*)d_in[20];
    const float* ff_b1    = (const float*)d_in[21];
    const float* ff_w2    = (const float*)d_in[22];
    const float* ff_b2    = (const float*)d_in[23];
    const float* fn_pre_g = (const float*)d_in[24];
    const float* fn_pre_b = (const float*)d_in[25];
    const float* fn_g     = (const float*)d_in[26];
    const float* fn_b     = (const float*)d_in[27];
    const float* traj_w   = (const float*)d_in[28];
    const float* traj_b   = (const float*)d_in[29];

    // ---- workspace layout (offsets unchanged from R26; scratch region now unused) ----
    char* ws = (char*)d_ws;
    float*          h        = (float*)ws;                           //  83,886,080 B
    float*          stats    = (float*)(ws + 83886080);              //   2,621,440 B
    unsigned short* wqT      = (unsigned short*)(ws + 212336640);    //     294,912 B
    unsigned short* outT     = (unsigned short*)(ws + 212631552);    //      98,304 B
    unsigned short* ff1T     = (unsigned short*)(ws + 212729856);    //     393,216 B
    unsigned short* ff2T     = (unsigned short*)(ws + 213123072);    //     393,216 B
    float*          partials = (float*)(ws + 213516288);             //     163,840 B
    float*          scal     = (float*)(ws + 213680128);             //         256 B

    pack_w_k<<<2304, 256, 0, stream>>>(qt_w, kt_w, qs_w, ks_w, v_w, out_w, ff_w1, ff_w2,
                                       wqT, outT, ff1T, ff2T);
    // fused embedding + mln1-of-layer-0 stats
    embed_stats_k<<<40960, 256, 0, stream>>>(x, embed_w, embed_b, pos,
                                             n1_pre_g, n1_pre_b, h, stats, partials);
    reduce_eps_k<<<1, 1024, 0, stream>>>(partials, 40960, scal);

    for (int i = 0; i < NLAY; ++i) {
        qkvattn_k<<<4096, 256, 0, stream>>>(
            h, stats, scal,
            n1_pre_g + i*128, n1_pre_b + i*128, n1_g + i*128, n1_b + i*128,
            wqT + (size_t)i*49152,
            w_sigma + i,
            outT + (size_t)i*16384, out_b + i*128,
            h, n2_pre_g + i*128, n2_pre_b + i*128,
            stats, partials);
        reduce_eps_k<<<1, 1024, 0, stream>>>(partials, 4096, scal);
        const float* npg = (i < NLAY-1) ? (n1_pre_g + (i+1)*128) : fn_pre_g;
        const float* npb = (i < NLAY-1) ? (n1_pre_b + (i+1)*128) : fn_pre_b;
        ffn_k<<<1280, 512, 0, stream>>>(
            h, stats, scal,
            n2_pre_g + i*128, n2_pre_b + i*128, n2_g + i*128, n2_b + i*128,
            ff1T + (size_t)i*65536, ff_b1 + i*512,
            ff2T + (size_t)i*65536, ff_b2 + i*128, h,
            npg, npb, stats, partials);
        reduce_eps_k<<<1, 1024, 0, stream>>>(partials, 1280, scal);
    }

    // ---- final mln (fused) + head ----
    head_k<<<4096, 128, 0, stream>>>(h, stats, scal, fn_pre_g, fn_pre_b, fn_g, fn_b,
                                     traj_w, traj_b, (float*)d_out);
}

// Round 30
// 811.068 us; speedup vs baseline: 1.1386x; 1.1386x over previous
//
#include <hip/hip_runtime.h>
#include <hip/hip_bf16.h>

// Model dims (fixed)
#define DIMM 128
#define TT   40
#define BB   4096
#define NTOK (BB*TT)           // 163840
#define NLAY 3

typedef float f4 __attribute__((ext_vector_type(4)));
typedef float f32x4 __attribute__((ext_vector_type(4)));
typedef short bf16x8 __attribute__((ext_vector_type(8)));

__device__ __forceinline__ float bf2f(unsigned short u) {
    union { unsigned int i; float f; } v; v.i = ((unsigned int)u) << 16; return v.f;
}
__device__ __forceinline__ unsigned short f2bu(float f) {
    __hip_bfloat16 h = __float2bfloat16(f);
    return *reinterpret_cast<unsigned short*>(&h);
}
// tanh-form gelu via sigmoid
__device__ __forceinline__ float gelu_f(float v) {
    float z = 1.5957691216057308f * fmaf(0.044715f * v * v, v, v);
    return v / (1.f + __expf(-z));
}

// per-row mln stats from registers (16 lanes hold full row)
__device__ __forceinline__ void mln_rowstat(
    const float* v, const float* pgv, const float* pbv,
    float& m, float& rstd, float& mq)
{
    float s1 = 0.f, s2 = 0.f;
    #pragma unroll
    for (int nf = 0; nf < 8; ++nf) { s1 += v[nf]; s2 += v[nf]*v[nf]; }
    #pragma unroll
    for (int o = 1; o < 16; o <<= 1) { s1 += __shfl_xor(s1, o); s2 += __shfl_xor(s2, o); }
    m = s1 * (1.f/128.f);
    float var = s2 * (1.f/128.f) - m*m;
    rstd = rsqrtf(fmaxf(var, 0.f) + 1e-5f);
    float q = 0.f;
    #pragma unroll
    for (int nf = 0; nf < 8; ++nf) {
        float yv = (v[nf] - m) * rstd * pgv[nf] + pbv[nf];
        q += (nf < 2 ? -(yv*yv) : (yv*yv));
    }
    #pragma unroll
    for (int o = 1; o < 16; o <<= 1) q += __shfl_xor(q, o);
    mq = q;
}

// build per-wave MFMA A-fragments directly from h with the mln transform (2 row-tiles)
__device__ __forceinline__ void build_mln_frags(
    bf16x8 a[2][4], const float* __restrict__ h, int row_mf0, int row_mf1,
    const float* __restrict__ stats, float eps,
    const float* __restrict__ pg, const float* __restrict__ pb,
    const float* __restrict__ gg, const float* __restrict__ gb, int q)
{
    int rows[2] = { row_mf0, row_mf1 };
    float rss3[2], mm[2], s3v[2];
    #pragma unroll
    for (int mf = 0; mf < 2; ++mf) {
        int r = rows[mf];
        float m  = stats[(size_t)r*4 + 0];
        float rs = stats[(size_t)r*4 + 1];
        float mq = stats[(size_t)r*4 + 2];
        float s3 = 1.f / (sqrtf(fabsf(mq) + eps) + eps);
        rss3[mf] = rs * s3; mm[mf] = -m * rss3[mf]; s3v[mf] = s3;
    }
    #pragma unroll
    for (int ks = 0; ks < 4; ++ks) {
        int c0 = ks*32 + q*8;
        float al[8], be[8], gbv[8];
        #pragma unroll
        for (int j = 0; j < 8; ++j) {
            float g = gg[c0+j];
            al[j] = g * pg[c0+j]; be[j] = g * pb[c0+j]; gbv[j] = gb[c0+j];
        }
        #pragma unroll
        for (int mf = 0; mf < 2; ++mf) {
            int r = rows[mf];
            f4 x0 = *(const f4*)(h + (size_t)r*128 + c0);
            f4 x1 = *(const f4*)(h + (size_t)r*128 + c0 + 4);
            union { unsigned short u[8]; bf16x8 v; } o;
            #pragma unroll
            for (int j = 0; j < 4; ++j) {
                float t0 = fmaf(x0[j], rss3[mf], mm[mf]);
                float t1 = fmaf(x1[j], rss3[mf], mm[mf]);
                o.u[j]   = f2bu(fmaf(al[j],   t0, fmaf(be[j],   s3v[mf], gbv[j])));
                o.u[j+4] = f2bu(fmaf(al[j+4], t1, fmaf(be[j+4], s3v[mf], gbv[j+4])));
            }
            a[mf][ks] = o.v;
        }
    }
}

// single-row mln A-fragments (16-row wave tile)
__device__ __forceinline__ void build_mln_frags1(
    bf16x8 a[4], const float* __restrict__ h, int row,
    const float* __restrict__ stats, float eps,
    const float* __restrict__ pg, const float* __restrict__ pb,
    const float* __restrict__ gg, const float* __restrict__ gb, int q)
{
    float m  = stats[(size_t)row*4 + 0];
    float rs = stats[(size_t)row*4 + 1];
    float mq = stats[(size_t)row*4 + 2];
    float s3 = 1.f / (sqrtf(fabsf(mq) + eps) + eps);
    float rss3 = rs * s3, mm = -m * rss3;
    #pragma unroll
    for (int ks = 0; ks < 4; ++ks) {
        int c0 = ks*32 + q*8;
        f4 x0 = *(const f4*)(h + (size_t)row*128 + c0);
        f4 x1 = *(const f4*)(h + (size_t)row*128 + c0 + 4);
        union { unsigned short u[8]; bf16x8 v; } o;
        #pragma unroll
        for (int j = 0; j < 4; ++j) {
            float g0 = gg[c0+j], g1 = gg[c0+j+4];
            float t0 = fmaf(x0[j], rss3, mm);
            float t1 = fmaf(x1[j], rss3, mm);
            o.u[j]   = f2bu(fmaf(g0 * pg[c0+j],   t0, fmaf(g0 * pb[c0+j],   s3, gb[c0+j])));
            o.u[j+4] = f2bu(fmaf(g1 * pg[c0+j+4], t1, fmaf(g1 * pb[c0+j+4], s3, gb[c0+j+4])));
        }
        a[ks] = o.v;
    }
}

// ---------------- pack ALL weights to bf16, transposed W^T[n][k] ----------------
__global__ __launch_bounds__(256) void pack_w_k(
    const float* __restrict__ qt, const float* __restrict__ kt,
    const float* __restrict__ qs, const float* __restrict__ ks,
    const float* __restrict__ vw, const float* __restrict__ ow,
    const float* __restrict__ w1, const float* __restrict__ w2,
    unsigned short* __restrict__ wqT, unsigned short* __restrict__ outT,
    unsigned short* __restrict__ ff1T, unsigned short* __restrict__ ff2T)
{
    int idx = blockIdx.x * 256 + threadIdx.x;          // 589824 total
    if (idx < 147456) {
        int i = idx / 49152, r = idx % 49152;
        int n = r / 128, k = r % 128;
        float v;
        if (n < 32)        v = qt[i*4096  + k*32  + n];
        else if (n < 64)   v = kt[i*4096  + k*32  + (n-32)];
        else if (n < 160)  v = qs[i*12288 + k*96  + (n-64)];
        else if (n < 256)  v = ks[i*12288 + k*96  + (n-160)];
        else               v = vw[i*16384 + k*128 + (n-256)];
        wqT[idx] = f2bu(v);
    } else if (idx < 196608) {
        int j = idx - 147456;
        int i = j / 16384, r = j % 16384;
        int n = r / 128, k = r % 128;
        outT[j] = f2bu(ow[i*16384 + k*128 + n]);
    } else if (idx < 393216) {
        int j = idx - 196608;
        int i = j / 65536, r = j % 65536;
        int n = r / 128, k = r % 128;
        ff1T[j] = f2bu(w1[i*65536 + k*512 + n]);
    } else {
        int j = idx - 393216;
        int i = j / 65536, r = j % 65536;
        int n = r / 512, k = r % 512;
        ff2T[j] = f2bu(w2[i*65536 + k*128 + n]);
    }
}

// ---------------- fused embedding + mln1 stats (layer 0) ----------------
__global__ __launch_bounds__(256) void embed_stats_k(
    const float* __restrict__ x, const float* __restrict__ ew,
    const float* __restrict__ eb, const float* __restrict__ pos,
    const float* __restrict__ pg, const float* __restrict__ pb,
    float* __restrict__ h, float* __restrict__ stats, float* __restrict__ partials)
{
    int wid = threadIdx.x >> 6, lane = threadIdx.x & 63;
    int tok = blockIdx.x * 4 + wid;
    int t = tok % TT;
    const float* xr = x + (size_t)tok * 6;
    float xv[6];
    #pragma unroll
    for (int k = 0; k < 6; ++k) xv[k] = xr[k];
    int d0 = lane, d1 = lane + 64;
    float x0 = eb[d0] + pos[t*128 + d0];
    float x1 = eb[d1] + pos[t*128 + d1];
    #pragma unroll
    for (int k = 0; k < 6; ++k) {
        x0 += xv[k] * ew[k*128 + d0];
        x1 += xv[k] * ew[k*128 + d1];
    }
    h[(size_t)tok*128 + d0] = x0;
    h[(size_t)tok*128 + d1] = x1;

    float s = x0 + x1;
    #pragma unroll
    for (int o = 32; o > 0; o >>= 1) s += __shfl_xor(s, o);
    float m = s * (1.f / 128.f);
    float e0 = x0 - m, e1 = x1 - m;
    float v = e0*e0 + e1*e1;
    #pragma unroll
    for (int o = 32; o > 0; o >>= 1) v += __shfl_xor(v, o);
    float rstd = rsqrtf(v * (1.f / 128.f) + 1e-5f);
    float y0 = e0 * rstd * pg[lane]      + pb[lane];
    float y1 = e1 * rstd * pg[lane + 64] + pb[lane + 64];
    float q = (lane < 32 ? -(y0*y0) : (y0*y0)) + y1*y1;
    #pragma unroll
    for (int o = 32; o > 0; o >>= 1) q += __shfl_xor(q, o);
    if (lane == 0) {
        stats[(size_t)tok*4 + 0] = m;
        stats[(size_t)tok*4 + 1] = rstd;
        stats[(size_t)tok*4 + 2] = q;
    }
    __shared__ float pm[4];
    if (lane == 0) pm[wid] = fabsf(q);
    __syncthreads();
    if (threadIdx.x == 0) partials[blockIdx.x] = (pm[0] + pm[1]) + (pm[2] + pm[3]);
}

// ---------------- reduce partials -> eps scalar ----------------
__global__ __launch_bounds__(1024) void reduce_eps_k(
    const float* __restrict__ partials, int n, float* __restrict__ scal)
{
    float s = 0.f;
    for (int i = threadIdx.x; i < n; i += 1024) s += partials[i];
    __shared__ float sm[1024];
    sm[threadIdx.x] = s;
    __syncthreads();
    for (int o = 512; o > 0; o >>= 1) {
        if (threadIdx.x < o) sm[threadIdx.x] += sm[threadIdx.x + o];
        __syncthreads();
    }
    if (threadIdx.x == 0) {
        float mean = sm[0] / (float)NTOK;
        scal[0] = fmaxf(0.01f * mean, 1e-5f);
    }
}

// ---------------- QKV GEMM: 4-wave/128-row block; Wq tiles staged in swizzled LDS ----------------
__global__ __launch_bounds__(256) void qkv_k(
    const float* __restrict__ hsrc,
    const float* __restrict__ stats_in, const float* __restrict__ scal,
    const float* __restrict__ pg, const float* __restrict__ pb,
    const float* __restrict__ gg, const float* __restrict__ gb,
    const unsigned short* __restrict__ BT,    // [384][128] bf16
    unsigned short* __restrict__ obuf)        // [NTOK][384] bf16
{
    __shared__ unsigned char Wl[32768];       // [128 n][256 B], swz (row&7)<<4
    const int tid = threadIdx.x, wid = tid >> 6, lane = tid & 63;
    const int q = lane >> 4, l15 = lane & 15;
    const int row0 = blockIdx.x * 128;
    const int wrow = row0 + wid * 32;

    bf16x8 a[2][4];
    build_mln_frags(a, hsrc, wrow + l15, wrow + 16 + l15,
                    stats_in, scal[0], pg, pb, gg, gb, q);

    const unsigned char* BTb = (const unsigned char*)BT;
    for (int nc = 0; nc < 3; ++nc) {
        __syncthreads();
        {
            int row = tid >> 1, half = tid & 1;
            #pragma unroll
            for (int jj = 0; jj < 8; ++jj) {
                int colb = half*128 + jj*16;
                uint4 v = *(const uint4*)(BTb + (size_t)(nc*128 + row)*256 + colb);
                *(uint4*)(Wl + row*256 + (colb ^ ((row & 7) << 4))) = v;
            }
        }
        __syncthreads();
        f32x4 acc[2][8] = {};
        #pragma unroll
        for (int ks = 0; ks < 4; ++ks)
            #pragma unroll
            for (int nf = 0; nf < 8; ++nf) {
                int row = nf*16 + l15;
                bf16x8 b = *(const bf16x8*)(Wl + row*256 + ((ks*64 + q*16) ^ ((row & 7) << 4)));
                #pragma unroll
                for (int mf = 0; mf < 2; ++mf)
                    acc[mf][nf] = __builtin_amdgcn_mfma_f32_16x16x32_bf16(a[mf][ks], b, acc[mf][nf], 0, 0, 0);
            }
        #pragma unroll
        for (int mf = 0; mf < 2; ++mf)
            #pragma unroll
            for (int r = 0; r < 4; ++r) {
                int row = wrow + mf*16 + q*4 + r;
                #pragma unroll
                for (int nf = 0; nf < 8; ++nf)
                    obuf[(size_t)row*384 + nc*128 + nf*16 + l15] = f2bu(acc[mf][nf][r]);
            }
    }
}

// ---------------- fused MFMA attention + out-proj + mln2 stats ----------------
__global__ __launch_bounds__(256) void attn_k(
    const unsigned short* __restrict__ scratch, const float* __restrict__ wsp,
    const unsigned short* __restrict__ outT,   // [128 n][128 k] bf16
    const float* __restrict__ bias,
    float* __restrict__ hres,
    const float* __restrict__ pre_g, const float* __restrict__ pre_b,
    float* __restrict__ stats, float* __restrict__ partials)
{
    // phase1: Vt = lds[0..16384), Pl = lds[16384..40960)
    // phase2: Ol = lds[0..12288), Wl = lds[12288..45056)
    __shared__ unsigned char lds[45056];
    __shared__ float sm[16];
    const int b = blockIdx.x, tid = threadIdx.x;
    const unsigned short* base = scratch + (size_t)b * TT * 384;

    unsigned char* VtL = lds;
    unsigned char* PlL = lds + 16384;

    // zero P pad cols 48..63
    for (int e = tid; e < 1536; e += 256) {
        int hh = e / 384, rem = e - hh*384;
        int row = rem >> 3, c = rem & 7;
        int byte = hh*6144 + ((row*128 + 96 + 4*c) ^ ((row & 7) << 4));
        *(unsigned int*)(PlL + byte) = 0u;
    }
    // zero V pad s 40..63
    for (int e = tid; e < 1536; e += 256) {
        int hh = e / 384, rem = e - hh*384;
        int d = rem / 12, sc2 = rem - d*12;
        int s = 40 + 2*sc2;
        int byte = hh*4096 + ((d*128 + s*2) ^ (((d >> 3) & 7) << 4));
        *(unsigned int*)(VtL + byte) = 0u;
    }
    // stage V transposed
    for (int e = tid; e < 640; e += 256) {
        int s = e >> 4, ck = e & 15;
        union { bf16x8 v; unsigned short u[8]; } g;
        g.v = *(const bf16x8*)(base + (size_t)s*384 + 256 + ck*8);
        int hh = ck >> 2, d0 = (ck & 3) * 8;
        #pragma unroll
        for (int j = 0; j < 8; ++j) {
            int d = d0 + j;
            int byte = hh*4096 + ((d*128 + s*2) ^ (((d >> 3) & 7) << 4));
            *(unsigned short*)(VtL + byte) = g.u[j];
        }
    }
    __syncthreads();

    const int h = tid >> 6, lane = tid & 63;
    const int l15 = lane & 15, q4 = lane >> 4;
    const unsigned char* Vt = VtL + h*4096;
    unsigned char* Pl = PlL + h*6144;

    const int qcol = (h == 0) ? 0  : 32  + h*32;
    const int kcol = (h == 0) ? 32 : 128 + h*32;
    const float scale = 0.17677669529663687f;   // 32^-0.5
    const float wmul = (h == 0) ? (-scale / (1.f + __expf(-wsp[0]))) : scale;

    bf16x8 aq[3], bk[3];
    #pragma unroll
    for (int mt = 0; mt < 3; ++mt) {
        int t = l15 + 16*mt; if (t > 39) t = 39;
        aq[mt] = *(const bf16x8*)(base + (size_t)t*384 + qcol + q4*8);
    }
    #pragma unroll
    for (int jt = 0; jt < 3; ++jt) {
        int s = l15 + 16*jt; if (s > 39) s = 39;
        bk[jt] = *(const bf16x8*)(base + (size_t)s*384 + kcol + q4*8);
    }
    f32x4 sc[3][3] = {};
    #pragma unroll
    for (int mt = 0; mt < 3; ++mt)
        #pragma unroll
        for (int jt = 0; jt < 3; ++jt)
            sc[mt][jt] = __builtin_amdgcn_mfma_f32_16x16x32_bf16(aq[mt], bk[jt], sc[mt][jt], 0, 0, 0);

    const bool mask2 = (l15 >= 8);
    float inv[3][4];
    #pragma unroll
    for (int mt = 0; mt < 3; ++mt) {
        #pragma unroll
        for (int r = 0; r < 4; ++r) {
            float s0 = wmul * sc[mt][0][r];
            float s1 = wmul * sc[mt][1][r];
            float s2 = mask2 ? -1e30f : wmul * sc[mt][2][r];
            float mx = fmaxf(fmaxf(s0, s1), s2);
            #pragma unroll
            for (int o = 1; o < 16; o <<= 1) mx = fmaxf(mx, __shfl_xor(mx, o));
            float e0 = __expf(s0 - mx), e1 = __expf(s1 - mx), e2 = __expf(s2 - mx);
            float sum = e0 + e1 + e2;
            #pragma unroll
            for (int o = 1; o < 16; o <<= 1) sum += __shfl_xor(sum, o);
            inv[mt][r] = 1.f / sum;
            int row = 16*mt + 4*q4 + r;
            int rsw = (row & 7) << 4;
            *(unsigned short*)(Pl + ((row*128 + l15*2       ) ^ rsw)) = f2bu(e0);
            *(unsigned short*)(Pl + ((row*128 + 32 + l15*2  ) ^ rsw)) = f2bu(e1);
            *(unsigned short*)(Pl + ((row*128 + 64 + l15*2  ) ^ rsw)) = f2bu(e2);
        }
    }

    f32x4 oacc[3][2] = {};
    #pragma unroll
    for (int ks2 = 0; ks2 < 2; ++ks2) {
        bf16x8 bv[2];
        #pragma unroll
        for (int nt = 0; nt < 2; ++nt) {
            int d = l15 + 16*nt;
            bv[nt] = *(const bf16x8*)(Vt + ((d*128 + 64*ks2 + 16*q4) ^ (((d >> 3) & 7) << 4)));
        }
        #pragma unroll
        for (int mt = 0; mt < 3; ++mt) {
            int row = l15 + 16*mt;
            bf16x8 pa = *(const bf16x8*)(Pl + ((row*128 + 64*ks2 + 16*q4) ^ ((row & 7) << 4)));
            #pragma unroll
            for (int nt = 0; nt < 2; ++nt)
                oacc[mt][nt] = __builtin_amdgcn_mfma_f32_16x16x32_bf16(pa, bv[nt], oacc[mt][nt], 0, 0, 0);
        }
    }

    // -------- phase 2: out-proj fused --------
    __syncthreads();          // all V/P reads done; lds reusable
    unsigned char* Ol = lds;              // [48 row][256 B], swz (row&7)<<4
    unsigned char* Wl = lds + 12288;      // [128 n][256 B],  swz (row&7)<<4

    #pragma unroll
    for (int mt = 0; mt < 3; ++mt) {
        #pragma unroll
        for (int r = 0; r < 4; ++r) {
            int row = 16*mt + 4*q4 + r;
            float iv = inv[mt][r];
            int rsw = (row & 7) << 4;
            #pragma unroll
            for (int nt = 0; nt < 2; ++nt) {
                int colb = (h*32 + nt*16 + l15) * 2;
                *(unsigned short*)(Ol + ((row*256 + colb) ^ rsw)) = f2bu(oacc[mt][nt][r] * iv);
            }
        }
    }
    // stage Wout
    {
        const unsigned char* BTb = (const unsigned char*)outT;
        int row = tid >> 1, half = tid & 1;
        #pragma unroll
        for (int jj = 0; jj < 8; ++jj) {
            int colb = half*128 + jj*16;
            uint4 v = *(const uint4*)(BTb + (size_t)row*256 + colb);
            *(uint4*)(Wl + row*256 + (colb ^ ((row & 7) << 4))) = v;
        }
    }
    if (h == 3 && l15 == 0) sm[12 + q4] = 0.f;
    __syncthreads();

    if (h < 3) {
        int arow = 16*h + l15;
        bf16x8 ao[4];
        #pragma unroll
        for (int ks = 0; ks < 4; ++ks)
            ao[ks] = *(const bf16x8*)(Ol + arow*256 + ((ks*64 + q4*16) ^ ((arow & 7) << 4)));
        f32x4 oc[8] = {};
        #pragma unroll
        for (int ks = 0; ks < 4; ++ks)
            #pragma unroll
            for (int nf = 0; nf < 8; ++nf) {
                int brow = nf*16 + l15;
                bf16x8 bo = *(const bf16x8*)(Wl + brow*256 + ((ks*64 + q4*16) ^ ((brow & 7) << 4)));
                oc[nf] = __builtin_amdgcn_mfma_f32_16x16x32_bf16(ao[ks], bo, oc[nf], 0, 0, 0);
            }

        float bv[8], pgv[8], pbv[8];
        #pragma unroll
        for (int nf = 0; nf < 8; ++nf) {
            int c = nf*16 + l15;
            bv[nf] = bias[c]; pgv[nf] = pre_g[c]; pbv[nf] = pre_b[c];
        }
        float amq = 0.f;
        #pragma unroll
        for (int r = 0; r < 4; ++r) {
            int t = 16*h + 4*q4 + r;
            if (t < 40) {
                int row = b*TT + t;
                float* hr = hres + (size_t)row*128;
                float v[8];
                #pragma unroll
                for (int nf = 0; nf < 8; ++nf) {
                    float hv = hr[nf*16 + l15] + oc[nf][r] + bv[nf];
                    hr[nf*16 + l15] = hv;
                    v[nf] = hv;
                }
                float m, rstd, mq;
                mln_rowstat(v, pgv, pbv, m, rstd, mq);
                if (l15 == 0) {
                    stats[(size_t)row*4 + 0] = m;
                    stats[(size_t)row*4 + 1] = rstd;
                    stats[(size_t)row*4 + 2] = mq;
                }
                amq += fabsf(mq);
            }
        }
        if (l15 == 0) sm[h*4 + q4] = amq;
    }
    __syncthreads();
    if (tid == 0) {
        float s = 0.f;
        #pragma unroll
        for (int j = 0; j < 16; ++j) s += sm[j];
        partials[b] = s;
    }
}

// ---------------- fused FFN: 8-wave/128-row block (16 rows/wave); W tiles in swizzled LDS ----------------
__global__ __launch_bounds__(512) void ffn_k(
    const float* __restrict__ hsrc,
    const float* __restrict__ stats_in, const float* __restrict__ scal,
    const float* __restrict__ m2_pre_g, const float* __restrict__ m2_pre_b,
    const float* __restrict__ m2_g, const float* __restrict__ m2_b,
    const unsigned short* __restrict__ W1T,   // [512][128] bf16
    const float* __restrict__ b1,
    const unsigned short* __restrict__ W2T,   // [128][512] bf16
    const float* __restrict__ b2,
    float* __restrict__ h,
    const float* __restrict__ pre_g, const float* __restrict__ pre_b,
    float* __restrict__ stats, float* __restrict__ partials)
{
    __shared__ unsigned char W1l[16384];      // [64 mid][256 B], swz (row&7)<<4
    __shared__ unsigned char W2l[16384];      // [128 n][128 B],  swz (row&7)<<4
    __shared__ unsigned char Ps[8][16*144];   // per-wave gelu mid (16 rows)
    __shared__ float sm[32];
    const int tid = threadIdx.x, wid = tid >> 6, lane = tid & 63;
    const int q = lane >> 4, l15 = lane & 15;
    const int row0 = blockIdx.x * 128;
    const int wrow = row0 + wid * 16;
    unsigned char* Pw = Ps[wid];

    bf16x8 a[4];
    build_mln_frags1(a, hsrc, wrow + l15,
                     stats_in, scal[0], m2_pre_g, m2_pre_b, m2_g, m2_b, q);

    float b2v[8];
    #pragma unroll
    for (int nf = 0; nf < 8; ++nf) b2v[nf] = b2[nf*16 + l15];

    f32x4 acc2[8] = {};
    const unsigned char* W1b = (const unsigned char*)W1T;
    const unsigned char* W2b = (const unsigned char*)W2T;

    for (int c = 0; c < 8; ++c) {
        __syncthreads();
        // stage W1 chunk: 64 mid-rows x 256 B (512 threads, 32B each)
        {
            int row = tid >> 3, seg = tid & 7;
            #pragma unroll
            for (int jj = 0; jj < 2; ++jj) {
                int colb = seg*32 + jj*16;
                uint4 v = *(const uint4*)(W1b + (size_t)(c*64 + row)*256 + colb);
                *(uint4*)(W1l + row*256 + (colb ^ ((row & 7) << 4))) = v;
            }
        }
        // stage W2 chunk: 128 n-rows x 128 B (512 threads, 32B each)
        {
            int row = tid >> 2, seg = tid & 3;
            #pragma unroll
            for (int jj = 0; jj < 2; ++jj) {
                int colb = seg*32 + jj*16;
                uint4 v = *(const uint4*)(W2b + (size_t)row*1024 + c*128 + colb);
                *(uint4*)(W2l + row*128 + (colb ^ ((row & 7) << 4))) = v;
            }
        }
        __syncthreads();
        // gemm1: P = A @ W1c  (bias folded into acc init)
        float bbv[4];
        #pragma unroll
        for (int nf = 0; nf < 4; ++nf) bbv[nf] = b1[c*64 + nf*16 + l15];
        f32x4 acc1[4];
        #pragma unroll
        for (int nf = 0; nf < 4; ++nf)
            acc1[nf] = f32x4{bbv[nf], bbv[nf], bbv[nf], bbv[nf]};
        #pragma unroll
        for (int ks = 0; ks < 4; ++ks)
            #pragma unroll
            for (int nf = 0; nf < 4; ++nf) {
                int row = nf*16 + l15;
                bf16x8 b = *(const bf16x8*)(W1l + row*256 + ((ks*64 + q*16) ^ ((row & 7) << 4)));
                acc1[nf] = __builtin_amdgcn_mfma_f32_16x16x32_bf16(a[ks], b, acc1[nf], 0, 0, 0);
            }
        #pragma unroll
        for (int nf = 0; nf < 4; ++nf) {
            #pragma unroll
            for (int r = 0; r < 4; ++r) {
                float v = gelu_f(acc1[nf][r]);
                *(unsigned short*)(Pw + (q*4 + r)*144 + (nf*16 + l15)*2) = f2bu(v);
            }
        }
        #pragma unroll
        for (int ks2 = 0; ks2 < 2; ++ks2) {
            bf16x8 a2 = *(const bf16x8*)(Pw + l15*144 + ks2*64 + q*16);
            #pragma unroll
            for (int nf = 0; nf < 8; ++nf) {
                int row = nf*16 + l15;
                bf16x8 b = *(const bf16x8*)(W2l + row*128 + ((ks2*64 + q*16) ^ ((row & 7) << 4)));
                acc2[nf] = __builtin_amdgcn_mfma_f32_16x16x32_bf16(a2, b, acc2[nf], 0, 0, 0);
            }
        }
    }

    float pgv[8], pbv[8];
    #pragma unroll
    for (int nf = 0; nf < 8; ++nf) { pgv[nf] = pre_g[nf*16 + l15]; pbv[nf] = pre_b[nf*16 + l15]; }
    float amq = 0.f;
    #pragma unroll
    for (int r = 0; r < 4; ++r) {
        int row = wrow + q*4 + r;
        float* hr = h + (size_t)row*128;
        float v[8];
        #pragma unroll
        for (int nf = 0; nf < 8; ++nf) {
            float hv = hr[nf*16 + l15] + acc2[nf][r] + b2v[nf];
            hr[nf*16 + l15] = hv;
            v[nf] = hv;
        }
        float m, rstd, mq;
        mln_rowstat(v, pgv, pbv, m, rstd, mq);
        if (l15 == 0) {
            stats[(size_t)row*4 + 0] = m;
            stats[(size_t)row*4 + 1] = rstd;
            stats[(size_t)row*4 + 2] = mq;
        }
        amq += fabsf(mq);
    }
    if (l15 == 0) sm[wid*4 + q] = amq;
    __syncthreads();
    if (tid == 0) {
        float s = 0.f;
        #pragma unroll
        for (int j = 0; j < 32; ++j) s += sm[j];
        partials[blockIdx.x] = s;
    }
}

// ---------------- head: final mln (last token only) + @traj_w + traj_b ----------------
__global__ __launch_bounds__(128) void head_k(
    const float* __restrict__ h, const float* __restrict__ stats, const float* __restrict__ scal,
    const float* __restrict__ pg, const float* __restrict__ pb,
    const float* __restrict__ gg, const float* __restrict__ gb,
    const float* __restrict__ tw, const float* __restrict__ tb,
    float* __restrict__ out)
{
    int b = blockIdx.x, tid = threadIdx.x;
    int tok = b*TT + (TT - 1);
    __shared__ float ys[128];
    float eps = scal[0];
    float m  = stats[(size_t)tok*4 + 0];
    float rs = stats[(size_t)tok*4 + 1];
    float mq = stats[(size_t)tok*4 + 2];
    float s3 = 1.f / (sqrtf(fabsf(mq) + eps) + eps);
    float x = h[(size_t)tok*128 + tid];
    ys[tid] = gg[tid] * (((x - m) * rs * pg[tid] + pb[tid]) * s3) + gb[tid];
    __syncthreads();
    if (tid < 120) {
        float acc = tb[tid];
        #pragma unroll 4
        for (int d = 0; d < 128; ++d) acc += ys[d] * tw[d*120 + tid];
        out[(size_t)b*120 + tid] = acc;
    }
}

extern "C" void kernel_launch(void* const* d_in, const int* in_sizes, int n_in,
                              void* d_out, int out_size, void* d_ws, size_t ws_size,
                              hipStream_t stream) {
    const float* x        = (const float*)d_in[0];
    const float* embed_w  = (const float*)d_in[1];
    const float* embed_b  = (const float*)d_in[2];
    const float* pos      = (const float*)d_in[3];
    const float* qt_w     = (const float*)d_in[4];
    const float* kt_w     = (const float*)d_in[5];
    const float* qs_w     = (const float*)d_in[6];
    const float* ks_w     = (const float*)d_in[7];
    const float* v_w      = (const float*)d_in[8];
    const float* out_w    = (const float*)d_in[9];
    const float* out_b    = (const float*)d_in[10];
    const float* w_sigma  = (const float*)d_in[11];
    const float* n1_pre_g = (const float*)d_in[12];
    const float* n1_pre_b = (const float*)d_in[13];
    const float* n1_g     = (const float*)d_in[14];
    const float* n1_b     = (const float*)d_in[15];
    const float* n2_pre_g = (const float*)d_in[16];
    const float* n2_pre_b = (const float*)d_in[17];
    const float* n2_g     = (const float*)d_in[18];
    const float* n2_b     = (const float*)d_in[19];
    const float* ff_w1    = (const float*)d_in[20];
    const float* ff_b1    = (const float*)d_in[21];
    const float* ff_w2    = (const float*)d_in[22];
    const float* ff_b2    = (const float*)d_in[23];
    const float* fn_pre_g = (const float*)d_in[24];
    const float* fn_pre_b = (const float*)d_in[25];
    const float* fn_g     = (const float*)d_in[26];
    const float* fn_b     = (const float*)d_in[27];
    const float* traj_w   = (const float*)d_in[28];
    const float* traj_b   = (const float*)d_in[29];

    // ---- workspace layout (total ~213.7 MB, < proven 255 MB) ----
    char* ws = (char*)d_ws;
    float*          h        = (float*)ws;                           //  83,886,080 B
    float*          stats    = (float*)(ws + 83886080);              //   2,621,440 B
    unsigned short* scratch  = (unsigned short*)(ws + 86507520);     // 125,829,120 B (NTOK x 384 bf16)
    unsigned short* wqT      = (unsigned short*)(ws + 212336640);    //     294,912 B
    unsigned short* outT     = (unsigned short*)(ws + 212631552);    //      98,304 B
    unsigned short* ff1T     = (unsigned short*)(ws + 212729856);    //     393,216 B
    unsigned short* ff2T     = (unsigned short*)(ws + 213123072);    //     393,216 B
    float*          partials = (float*)(ws + 213516288);             //     163,840 B
    float*          scal     = (float*)(ws + 213680128);             //         256 B

    pack_w_k<<<2304, 256, 0, stream>>>(qt_w, kt_w, qs_w, ks_w, v_w, out_w, ff_w1, ff_w2,
                                       wqT, outT, ff1T, ff2T);
    // fused embedding + mln1-of-layer-0 stats
    embed_stats_k<<<40960, 256, 0, stream>>>(x, embed_w, embed_b, pos,
                                             n1_pre_g, n1_pre_b, h, stats, partials);
    reduce_eps_k<<<1, 1024, 0, stream>>>(partials, 40960, scal);

    for (int i = 0; i < NLAY; ++i) {
        qkv_k<<<1280, 256, 0, stream>>>(
            h, stats, scal,
            n1_pre_g + i*128, n1_pre_b + i*128, n1_g + i*128, n1_b + i*128,
            wqT + (size_t)i*49152, scratch);
        attn_k<<<4096, 256, 0, stream>>>(
            scratch, w_sigma + i,
            outT + (size_t)i*16384, out_b + i*128,
            h, n2_pre_g + i*128, n2_pre_b + i*128,
            stats, partials);
        reduce_eps_k<<<1, 1024, 0, stream>>>(partials, 4096, scal);
        const float* npg = (i < NLAY-1) ? (n1_pre_g + (i+1)*128) : fn_pre_g;
        const float* npb = (i < NLAY-1) ? (n1_pre_b + (i+1)*128) : fn_pre_b;
        ffn_k<<<1280, 512, 0, stream>>>(
            h, stats, scal,
            n2_pre_g + i*128, n2_pre_b + i*128, n2_g + i*128, n2_b + i*128,
            ff1T + (size_t)i*65536, ff_b1 + i*512,
            ff2T + (size_t)i*65536, ff_b2 + i*128, h,
            npg, npb, stats, partials);
        reduce_eps_k<<<1, 1024, 0, stream>>>(partials, 1280, scal);
    }

    // ---- final mln (fused) + head ----
    head_k<<<4096, 128, 0, stream>>>(h, stats, scal, fn_pre_g, fn_pre_b, fn_g, fn_b,
                                     traj_w, traj_b, (float*)d_out);
}